// Round 7
// baseline (41.458 us; speedup 1.0000x reference)
//
#include <hip/hip_runtime.h>
#include <math.h>

// Problem constants (B=1, C=64, H=W=256, N=4096, T=0.1)
#define HW2     65536
#define NLOC    4096
#define NROW    8192
#define CDIM    64
#define TINV    10.0f
#define EXP10   22026.465794806718f   // exp(1/T)
#define NP      64                    // 128-row panels
#define NPAIR   2080                  // NP*(NP+1)/2

#if __has_builtin(__builtin_amdgcn_exp2f)
#define ASCALE  14.426950408889634f   // 10 * log2(e)
#define EXPFN(x) __builtin_amdgcn_exp2f(x)
#else
#define ASCALE  10.0f
#define EXPFN(x) __expf(x)
#endif

typedef __attribute__((ext_vector_type(8))) short bf16x8;
typedef __attribute__((ext_vector_type(4))) float f32x4;
typedef unsigned short u16;

__device__ __forceinline__ unsigned short f2bf(float f) {
  unsigned u = __builtin_bit_cast(unsigned, f);
  u += 0x7FFFu + ((u >> 16) & 1u);   // RNE
  return (unsigned short)(u >> 16);
}
__device__ __forceinline__ float bf2f(unsigned u16v) {
  unsigned u = u16v << 16;
  return __builtin_bit_cast(float, u);
}

// ---------------------------------------------------------------------------
// Kernel TG (fused transpose+gather): block = (window of 64 positions, emb).
// 1) stage 64pos x 64ch f32->bf16 tile in LDS (transposed),
// 2) scan this emb's 4096 locations, LDS-list those landing in the window,
// 3) emit Ga/Gb rows straight from LDS.  embT never materialized.
// Deterministic: each gather-row i belongs to exactly one window; list order
// does not affect written values.
// ---------------------------------------------------------------------------
__global__ __launch_bounds__(256) void tgather_kernel(
    const float* __restrict__ emb0, const float* __restrict__ emb1,
    const float* __restrict__ loc0, const float* __restrict__ loc1,
    u16* __restrict__ Ga, u16* __restrict__ Gb) {
  __shared__ u16 T[64 * 72];          // [pos][ch], padded to 72
  __shared__ unsigned list[NLOC];     // worst-case cap: always correct
  __shared__ unsigned nE;

  const int tid = threadIdx.x;
  const int win = blockIdx.x;         // 0..1023
  const int eb  = blockIdx.y;         // emb select
  const float* emb = eb ? emb1 : emb0;
  const float* loc = eb ? loc1 : loc0;
  const int w0 = win * 64;

  if (tid == 0) nE = 0;

  // --- stage tile: read coalesced f32, store bf16 transposed ---
#pragma unroll
  for (int q = 0; q < 4; ++q) {
    const int c = q * 16 + (tid >> 4);
    const int x = tid & 15;
    float4 v = *reinterpret_cast<const float4*>(&emb[(size_t)c * HW2 + w0 + x * 4]);
    T[(x * 4 + 0) * 72 + c] = f2bf(v.x);
    T[(x * 4 + 1) * 72 + c] = f2bf(v.y);
    T[(x * 4 + 2) * 72 + c] = f2bf(v.z);
    T[(x * 4 + 3) * 72 + c] = f2bf(v.w);
  }
  __syncthreads();   // T complete, nE=0 visible

  // --- scan locations for this emb; collect hits in this window ---
  for (int it = tid; it < NLOC; it += 256) {
    float2 lv = *reinterpret_cast<const float2*>(&loc[it * 2]);
    int ind = (int)floorf(lv.x) * 256 + (int)floorf(lv.y);
    if ((ind >> 6) == win) {
      unsigned slot = atomicAdd(&nE, 1u);
      list[slot] = ((unsigned)it << 6) | (unsigned)(ind & 63);
    }
  }
  __syncthreads();

  // --- emit rows: 8 threads per entry, 16B per thread ---
  const int n = (int)nE;
  const int ibase = eb * NLOC;
  const int c8 = tid & 7;
  for (int s = (tid >> 3); s < n; s += 32) {
    const unsigned ent = list[s];
    const int i = (int)(ent >> 6) + ibase;
    const int w = (int)(ent & 63u);
    bf16x8 v = *reinterpret_cast<const bf16x8*>(&T[w * 72 + c8 * 8]);
    *reinterpret_cast<bf16x8*>(&Gb[(size_t)i * CDIM + c8 * 8]) = v;
    bf16x8 vs;
#pragma unroll
    for (int j = 0; j < 8; ++j) {
      float f = bf2f((unsigned short)v[j]);
      vs[j] = (short)f2bf(f * ASCALE);
    }
    *reinterpret_cast<bf16x8*>(&Ga[(size_t)i * CDIM + c8 * 8]) = vs;
  }
}

// ---------------------------------------------------------------------------
// Kernel G (fallback if ws too small): direct scattered gather.
// ---------------------------------------------------------------------------
__global__ __launch_bounds__(256) void gather_kernel(
    const float* __restrict__ emb0, const float* __restrict__ emb1,
    const float* __restrict__ loc0, const float* __restrict__ loc1,
    u16* __restrict__ Ga, u16* __restrict__ Gb) {
  int t = blockIdx.x * 256 + threadIdx.x;
  int i = t >> 6;
  int c = t & 63;
  const float* loc = (i < NLOC) ? loc0 : loc1;
  const float* emb = (i < NLOC) ? emb0 : emb1;
  int u = (i < NLOC) ? i : (i - NLOC);
  int ind = (int)floorf(loc[u * 2]) * 256 + (int)floorf(loc[u * 2 + 1]);
  float v = emb[(size_t)c * HW2 + ind];
  Gb[t] = f2bf(v);
  Ga[t] = f2bf(v * ASCALE);
}

// ---------------------------------------------------------------------------
// Staging: one 64-row x 128B tile, XOR seg-swizzle (measured 0 conflicts).
//   phys(row, seg) holds logical seg^(row&7); linear LDS dest + inverse-
//   swizzled global source (rule #21).
// ---------------------------------------------------------------------------
__device__ __forceinline__ void stage_tile(u16* Bs, const u16* __restrict__ Gb,
                                           int jb, int buf, int tid, int wave,
                                           int srow, int ssl) {
#pragma unroll
  for (int r = 0; r < 2; ++r) {
    const u16* src = Gb + (size_t)(jb + r * 32 + srow) * CDIM + ssl * 8;
#if __has_builtin(__builtin_amdgcn_global_load_lds)
    u16* dst = Bs + buf * 4096 + r * 2048 + wave * 512;
    __builtin_amdgcn_global_load_lds(
        (const __attribute__((address_space(1))) unsigned int*)src,
        (__attribute__((address_space(3))) unsigned int*)dst, 16, 0, 0);
#else
    bf16x8 tmp = *reinterpret_cast<const bf16x8*>(src);
    *reinterpret_cast<bf16x8*>(Bs + buf * 4096 + r * 2048 + tid * 8) = tmp;
#endif
  }
}

// ---------------------------------------------------------------------------
// Kernel S (triangular): block b -> panel pair (p,q), p<=q, 128x128 tile.
// Row-sums of exp-tile -> rowPart[p-rows][q]; col-sums -> rowPart[q-rows][p]
// (skipped for p==q).  Each (row, slot) written exactly once; no atomics.
// ---------------------------------------------------------------------------
__global__ __launch_bounds__(256) void simsum_tri_kernel(
    const u16* __restrict__ Ga, const u16* __restrict__ Gb,
    float* __restrict__ rowPart) {
  __shared__ u16 Bs[2 * 64 * CDIM];    // 16 KB: q-panel as two swizzled tiles
  __shared__ float colRed[4][128];     // 2 KB cross-wave col-sum reduce

  const int tid  = threadIdx.x;
  const int lane = tid & 63;
  const int wave = tid >> 6;
  const int lrow = lane & 15;
  const int kh   = lane >> 4;

  // Triangular decode: b -> (p,q).  cnt(p) = p*NP - p(p-1)/2 pairs before p.
  const int b = blockIdx.x;
  int p = (int)((129.0f - sqrtf(16641.0f - 8.0f * (float)b)) * 0.5f);
  if (p < 0) p = 0;
  if (p > NP - 1) p = NP - 1;
#pragma unroll
  for (int it = 0; it < 3; ++it) {
    if (p > 0 && (p * NP - p * (p - 1) / 2) > b) --p;
    else if (((p + 1) * NP - (p + 1) * p / 2) <= b) ++p;
  }
  const int q  = p + (b - (p * NP - p * (p - 1) / 2));
  const int p0 = p * 128, q0 = q * 128;
  const int i0 = p0 + wave * 32;       // wave owns 32 p-rows

  // A fragments (scaled), registers whole kernel.  bf16x8* steps 8 shorts.
  const bf16x8* arowA =
      reinterpret_cast<const bf16x8*>(Ga + (size_t)(i0 + lrow) * CDIM + kh * 8);
  const bf16x8* arowB =
      reinterpret_cast<const bf16x8*>(Ga + (size_t)(i0 + 16 + lrow) * CDIM + kh * 8);
  bf16x8 aA0 = arowA[0], aA1 = arowA[4];   // k [0,32), [32,64)
  bf16x8 aB0 = arowB[0], aB1 = arowB[4];

  // Stage whole q-panel (128 rows) as two 64-row tiles, one barrier.
  const int srow = tid >> 3;
  const int ssl  = (tid & 7) ^ (srow & 7);
  stage_tile(Bs, Gb, q0,      0, tid, wave, srow, ssl);
  stage_tile(Bs, Gb, q0 + 64, 1, tid, wave, srow, ssl);
  __syncthreads();   // compiler drains vmcnt before s_barrier

  const int sp0 = ((kh ^ (lrow & 7)) << 3);
  const int sp1 = (((4 + kh) ^ (lrow & 7)) << 3);

  float accA[4][4], accB[4][4];
#pragma unroll
  for (int nf = 0; nf < 4; ++nf)
#pragma unroll
    for (int r = 0; r < 4; ++r) { accA[nf][r] = 0.f; accB[nf][r] = 0.f; }
  float colAcc[2][4];

#pragma unroll
  for (int t = 0; t < 2; ++t) {
    const u16* bs = Bs + t * 4096;
#pragma unroll
    for (int nf = 0; nf < 4; ++nf) {
      const int rb = (nf * 16 + lrow) * CDIM;
      bf16x8 b0 = *reinterpret_cast<const bf16x8*>(bs + rb + sp0);
      bf16x8 b1 = *reinterpret_cast<const bf16x8*>(bs + rb + sp1);
      f32x4 z = {0.f, 0.f, 0.f, 0.f};
      f32x4 tA = __builtin_amdgcn_mfma_f32_16x16x32_bf16(aA0, b0, z, 0, 0, 0);
      tA = __builtin_amdgcn_mfma_f32_16x16x32_bf16(aA1, b1, tA, 0, 0, 0);
      f32x4 tB = __builtin_amdgcn_mfma_f32_16x16x32_bf16(aB0, b0, z, 0, 0, 0);
      tB = __builtin_amdgcn_mfma_f32_16x16x32_bf16(aB1, b1, tB, 0, 0, 0);
      float cp = 0.f;
#pragma unroll
      for (int r = 0; r < 4; ++r) {
        float eA = EXPFN(tA[r]);
        float eB = EXPFN(tB[r]);
        accA[nf][r] += eA;
        accB[nf][r] += eB;
        cp += eA + eB;
      }
      colAcc[t][nf] = cp;   // this (t,nf) visited once
    }
  }

  // Row-sums: reduce the 16 lanes (same kh) holding one row; slot q.
#pragma unroll
  for (int r = 0; r < 4; ++r) {
    float vA = (accA[0][r] + accA[1][r]) + (accA[2][r] + accA[3][r]);
    float vB = (accB[0][r] + accB[1][r]) + (accB[2][r] + accB[3][r]);
    vA += __shfl_xor(vA, 1, 16);
    vA += __shfl_xor(vA, 2, 16);
    vA += __shfl_xor(vA, 4, 16);
    vA += __shfl_xor(vA, 8, 16);
    vB += __shfl_xor(vB, 1, 16);
    vB += __shfl_xor(vB, 2, 16);
    vB += __shfl_xor(vB, 4, 16);
    vB += __shfl_xor(vB, 8, 16);
    if (lrow == 0) {
      rowPart[(size_t)(i0 + kh * 4 + r) * NP + q] = vA;
      rowPart[(size_t)(i0 + 16 + kh * 4 + r) * NP + q] = vB;
    }
  }

  // Col-sums (off-diagonal only): exp(sim_ij)=exp(sim_ji) feeds q-panel rows.
  if (p != q) {
#pragma unroll
    for (int t = 0; t < 2; ++t)
#pragma unroll
      for (int nf = 0; nf < 4; ++nf) {
        float c = colAcc[t][nf];
        c += __shfl_xor(c, 16, 64);   // reduce across kh row-groups
        c += __shfl_xor(c, 32, 64);
        if (kh == 0) colRed[wave][t * 64 + nf * 16 + lrow] = c;
      }
    __syncthreads();                  // p!=q is block-uniform -> legal
    if (tid < 128) {
      float s = (colRed[0][tid] + colRed[1][tid]) +
                (colRed[2][tid] + colRed[3][tid]);
      rowPart[(size_t)(q0 + tid) * NP + p] = s;
    }
  }
}

// ---------------------------------------------------------------------------
// Kernel F1: per-block partials; F2: one wave reduces the 64 partials.
// ---------------------------------------------------------------------------
__global__ __launch_bounds__(256) void finpart_kernel(
    const u16* __restrict__ Gb, const float* __restrict__ rowPart,
    float* __restrict__ partA, float* __restrict__ partB) {
  __shared__ float sA[256];
  __shared__ float sB[256];
  const int tid = threadIdx.x, b = blockIdx.x;

  float logAcc = 0.f;
  if (tid < 128) {
    const int row = b * 128 + tid;
    const float4* rp = reinterpret_cast<const float4*>(rowPart + (size_t)row * NP);
    float s = 0.f;
#pragma unroll
    for (int c = 0; c < NP / 4; ++c) {
      float4 v = rp[c];
      s += (v.x + v.y) + (v.z + v.w);
    }
    logAcc = logf(s - EXP10);
  }
  float cross = 0.f;
  if (tid < 64) {
    const int u = b * 64 + tid;
    const unsigned* r0 = reinterpret_cast<const unsigned*>(Gb + (size_t)u * CDIM);
    const unsigned* r1 =
        reinterpret_cast<const unsigned*>(Gb + (size_t)(u + NLOC) * CDIM);
#pragma unroll
    for (int c = 0; c < 32; ++c) {
      unsigned a = r0[c], bb = r1[c];
      cross += bf2f(a & 0xffffu) * bf2f(bb & 0xffffu) + bf2f(a >> 16) * bf2f(bb >> 16);
    }
  }
  sA[tid] = logAcc;
  sB[tid] = cross;
  __syncthreads();
  for (int s = 128; s > 0; s >>= 1) {
    if (tid < s) { sA[tid] += sA[tid + s]; sB[tid] += sB[tid + s]; }
    __syncthreads();
  }
  if (tid == 0) { partA[b] = sA[0]; partB[b] = sB[0]; }
}

__global__ __launch_bounds__(64) void fin2_kernel(
    const float* __restrict__ partA, const float* __restrict__ partB,
    float* __restrict__ out) {
  const int l = threadIdx.x;
  float a = partA[l];
  float c = partB[l];
#pragma unroll
  for (int s = 1; s < 64; s <<= 1) {
    a += __shfl_xor(a, s, 64);
    c += __shfl_xor(c, s, 64);
  }
  if (l == 0) out[0] = (a - 2.0f * TINV * c) / (float)NROW;
}

// ---------------------------------------------------------------------------
extern "C" void kernel_launch(void* const* d_in, const int* in_sizes, int n_in,
                              void* d_out, int out_size, void* d_ws, size_t ws_size,
                              hipStream_t stream) {
  const float* emb0 = (const float*)d_in[0];
  const float* emb1 = (const float*)d_in[1];
  const float* loc0 = (const float*)d_in[2];
  const float* loc1 = (const float*)d_in[3];
  float* out = (float*)d_out;
  char* ws = (char*)d_ws;

  // Layout: Ga 1MB | Gb 1MB | rowPart 2MB | partA/partB
  u16* Ga        = (u16*)ws;
  u16* Gb        = (u16*)(ws + (1ull << 20));
  float* rowPart = (float*)(ws + (2ull << 20));
  float* partA   = (float*)(ws + (4ull << 20));
  float* partB   = partA + 64;

  dim3 tg(HW2 / 64, 2);
  tgather_kernel<<<tg, 256, 0, stream>>>(emb0, emb1, loc0, loc1, Ga, Gb);

  simsum_tri_kernel<<<NPAIR, 256, 0, stream>>>(Ga, Gb, rowPart);
  finpart_kernel<<<64, 256, 0, stream>>>(Gb, rowPart, partA, partB);
  fin2_kernel<<<1, 64, 0, stream>>>(partA, partB, out);
}

// Round 8
// 36.894 us; speedup vs baseline: 1.1237x; 1.1237x over previous
//
#include <hip/hip_runtime.h>
#include <math.h>

// Problem constants (B=1, C=64, H=W=256, N=4096, T=0.1)
#define HW2     65536
#define NLOC    4096
#define NROW    8192
#define CDIM    64
#define TINV    10.0f
#define EXP10   22026.465794806718f   // exp(1/T)
#define NP      64                    // 128-row panels
#define NPAIR   2080                  // NP*(NP+1)/2

#if __has_builtin(__builtin_amdgcn_exp2f)
#define ASCALE  14.426950408889634f   // 10 * log2(e)
#define EXPFN(x) __builtin_amdgcn_exp2f(x)
#else
#define ASCALE  10.0f
#define EXPFN(x) __expf(x)
#endif

typedef __attribute__((ext_vector_type(8))) short bf16x8;
typedef __attribute__((ext_vector_type(4))) float f32x4;
typedef unsigned short u16;

__device__ __forceinline__ unsigned short f2bf(float f) {
  unsigned u = __builtin_bit_cast(unsigned, f);
  u += 0x7FFFu + ((u >> 16) & 1u);   // RNE
  return (unsigned short)(u >> 16);
}
__device__ __forceinline__ float bf2f(unsigned u16v) {
  unsigned u = u16v << 16;
  return __builtin_bit_cast(float, u);
}

// ---------------------------------------------------------------------------
// Kernel GC (channel-major gather): block = 64 gather-rows x 16 channels.
// A wave's 64 lanes read 64 random positions within ONE 256-KB channel slab
// (L2/DRAM-page friendly), assemble the G sub-tile in LDS, then write both
// Ga (scaled) and Gb coalesced.  No transposed copy of emb is materialized.
// Also zeroes the finpart completion counter (stream-ordered before use).
// ---------------------------------------------------------------------------
__global__ __launch_bounds__(256) void gatherc_kernel(
    const float* __restrict__ emb0, const float* __restrict__ emb1,
    const float* __restrict__ loc0, const float* __restrict__ loc1,
    u16* __restrict__ Ga, u16* __restrict__ Gb, unsigned* __restrict__ counter) {
  __shared__ int ind[64];
  __shared__ u16 Gs[64][18];          // pad 18: bank stride 9, coprime 32

  const int tid   = threadIdx.x;
  const int chunk = blockIdx.x;       // 0..127 -> rows chunk*64..+64
  const int cg    = blockIdx.y;       // 0..3   -> channels cg*16..+16
  const int eb    = chunk >> 6;
  const float* emb = eb ? emb1 : emb0;
  const float* loc = eb ? loc1 : loc0;

  if (chunk == 0 && cg == 0 && tid == 0) *counter = 0u;

  if (tid < 64) {
    const int u = (chunk & 63) * 64 + tid;
    float2 lv = *reinterpret_cast<const float2*>(&loc[u * 2]);
    ind[tid] = (int)floorf(lv.x) * 256 + (int)floorf(lv.y);
  }
  __syncthreads();

  const int row = tid & 63;
  const int cq  = tid >> 6;           // 0..3
  const int pos = ind[row];
#pragma unroll
  for (int k = 0; k < 4; ++k) {
    const int cl = cq + 4 * k;        // 0..15, each (row,cl) exactly once
    float v = emb[(size_t)(cg * 16 + cl) * HW2 + pos];
    Gs[row][cl] = f2bf(v);
  }
  __syncthreads();

  // write-out: tid<128 -> Gb, tid>=128 -> Ga (scaled); 16B per thread
  const int t  = tid & 127;
  const int r2 = t >> 1, h = t & 1;
  const size_t gi = (size_t)(chunk * 64 + r2) * CDIM + cg * 16 + h * 8;
  bf16x8 v = *reinterpret_cast<const bf16x8*>(&Gs[r2][h * 8]);
  if (tid < 128) {
    *reinterpret_cast<bf16x8*>(&Gb[gi]) = v;
  } else {
    bf16x8 vs;
#pragma unroll
    for (int j = 0; j < 8; ++j) {
      float f = bf2f((unsigned short)v[j]);
      vs[j] = (short)f2bf(f * ASCALE);
    }
    *reinterpret_cast<bf16x8*>(&Ga[gi]) = vs;
  }
}

// ---------------------------------------------------------------------------
// Staging: one 64-row x 128B tile, XOR seg-swizzle (measured 0 conflicts).
// ---------------------------------------------------------------------------
__device__ __forceinline__ void stage_tile(u16* Bs, const u16* __restrict__ Gb,
                                           int jb, int buf, int tid, int wave,
                                           int srow, int ssl) {
#pragma unroll
  for (int r = 0; r < 2; ++r) {
    const u16* src = Gb + (size_t)(jb + r * 32 + srow) * CDIM + ssl * 8;
#if __has_builtin(__builtin_amdgcn_global_load_lds)
    u16* dst = Bs + buf * 4096 + r * 2048 + wave * 512;
    __builtin_amdgcn_global_load_lds(
        (const __attribute__((address_space(1))) unsigned int*)src,
        (__attribute__((address_space(3))) unsigned int*)dst, 16, 0, 0);
#else
    bf16x8 tmp = *reinterpret_cast<const bf16x8*>(src);
    *reinterpret_cast<bf16x8*>(Bs + buf * 4096 + r * 2048 + tid * 8) = tmp;
#endif
  }
}

// ---------------------------------------------------------------------------
// Kernel S (triangular): block b -> panel pair (p,q), p<=q, 128x128 tile.
// Row-sums -> rowPart[p-rows][q]; col-sums -> rowPart[q-rows][p] (p!=q).
// ---------------------------------------------------------------------------
__global__ __launch_bounds__(256) void simsum_tri_kernel(
    const u16* __restrict__ Ga, const u16* __restrict__ Gb,
    float* __restrict__ rowPart) {
  __shared__ u16 Bs[2 * 64 * CDIM];    // 16 KB
  __shared__ float colRed[4][128];     // 2 KB

  const int tid  = threadIdx.x;
  const int lane = tid & 63;
  const int wave = tid >> 6;
  const int lrow = lane & 15;
  const int kh   = lane >> 4;

  const int b = blockIdx.x;
  int p = (int)((129.0f - sqrtf(16641.0f - 8.0f * (float)b)) * 0.5f);
  if (p < 0) p = 0;
  if (p > NP - 1) p = NP - 1;
#pragma unroll
  for (int it = 0; it < 3; ++it) {
    if (p > 0 && (p * NP - p * (p - 1) / 2) > b) --p;
    else if (((p + 1) * NP - (p + 1) * p / 2) <= b) ++p;
  }
  const int q  = p + (b - (p * NP - p * (p - 1) / 2));
  const int p0 = p * 128, q0 = q * 128;
  const int i0 = p0 + wave * 32;

  const bf16x8* arowA =
      reinterpret_cast<const bf16x8*>(Ga + (size_t)(i0 + lrow) * CDIM + kh * 8);
  const bf16x8* arowB =
      reinterpret_cast<const bf16x8*>(Ga + (size_t)(i0 + 16 + lrow) * CDIM + kh * 8);
  bf16x8 aA0 = arowA[0], aA1 = arowA[4];
  bf16x8 aB0 = arowB[0], aB1 = arowB[4];

  const int srow = tid >> 3;
  const int ssl  = (tid & 7) ^ (srow & 7);
  stage_tile(Bs, Gb, q0,      0, tid, wave, srow, ssl);
  stage_tile(Bs, Gb, q0 + 64, 1, tid, wave, srow, ssl);
  __syncthreads();

  const int sp0 = ((kh ^ (lrow & 7)) << 3);
  const int sp1 = (((4 + kh) ^ (lrow & 7)) << 3);

  float accA[4][4], accB[4][4];
#pragma unroll
  for (int nf = 0; nf < 4; ++nf)
#pragma unroll
    for (int r = 0; r < 4; ++r) { accA[nf][r] = 0.f; accB[nf][r] = 0.f; }
  float colAcc[2][4];

#pragma unroll
  for (int t = 0; t < 2; ++t) {
    const u16* bs = Bs + t * 4096;
#pragma unroll
    for (int nf = 0; nf < 4; ++nf) {
      const int rb = (nf * 16 + lrow) * CDIM;
      bf16x8 b0 = *reinterpret_cast<const bf16x8*>(bs + rb + sp0);
      bf16x8 b1 = *reinterpret_cast<const bf16x8*>(bs + rb + sp1);
      f32x4 z = {0.f, 0.f, 0.f, 0.f};
      f32x4 tA = __builtin_amdgcn_mfma_f32_16x16x32_bf16(aA0, b0, z, 0, 0, 0);
      tA = __builtin_amdgcn_mfma_f32_16x16x32_bf16(aA1, b1, tA, 0, 0, 0);
      f32x4 tB = __builtin_amdgcn_mfma_f32_16x16x32_bf16(aB0, b0, z, 0, 0, 0);
      tB = __builtin_amdgcn_mfma_f32_16x16x32_bf16(aB1, b1, tB, 0, 0, 0);
      float cp = 0.f;
#pragma unroll
      for (int r = 0; r < 4; ++r) {
        float eA = EXPFN(tA[r]);
        float eB = EXPFN(tB[r]);
        accA[nf][r] += eA;
        accB[nf][r] += eB;
        cp += eA + eB;
      }
      colAcc[t][nf] = cp;
    }
  }

#pragma unroll
  for (int r = 0; r < 4; ++r) {
    float vA = (accA[0][r] + accA[1][r]) + (accA[2][r] + accA[3][r]);
    float vB = (accB[0][r] + accB[1][r]) + (accB[2][r] + accB[3][r]);
    vA += __shfl_xor(vA, 1, 16);
    vA += __shfl_xor(vA, 2, 16);
    vA += __shfl_xor(vA, 4, 16);
    vA += __shfl_xor(vA, 8, 16);
    vB += __shfl_xor(vB, 1, 16);
    vB += __shfl_xor(vB, 2, 16);
    vB += __shfl_xor(vB, 4, 16);
    vB += __shfl_xor(vB, 8, 16);
    if (lrow == 0) {
      rowPart[(size_t)(i0 + kh * 4 + r) * NP + q] = vA;
      rowPart[(size_t)(i0 + 16 + kh * 4 + r) * NP + q] = vB;
    }
  }

  if (p != q) {
#pragma unroll
    for (int t = 0; t < 2; ++t)
#pragma unroll
      for (int nf = 0; nf < 4; ++nf) {
        float c = colAcc[t][nf];
        c += __shfl_xor(c, 16, 64);
        c += __shfl_xor(c, 32, 64);
        if (kh == 0) colRed[wave][t * 64 + nf * 16 + lrow] = c;
      }
    __syncthreads();                  // p!=q is block-uniform -> legal
    if (tid < 128) {
      float s = (colRed[0][tid] + colRed[1][tid]) +
                (colRed[2][tid] + colRed[3][tid]);
      rowPart[(size_t)(q0 + tid) * NP + p] = s;
    }
  }
}

// ---------------------------------------------------------------------------
// Kernel F (fused): per-block partials; last block (device-scope counter)
// reduces the 64 partials in fixed order and writes the scalar.
// ---------------------------------------------------------------------------
__global__ __launch_bounds__(256) void finpart_kernel(
    const u16* __restrict__ Gb, const float* __restrict__ rowPart,
    float* __restrict__ partA, float* __restrict__ partB,
    unsigned* __restrict__ counter, float* __restrict__ out) {
  __shared__ float sA[256];
  __shared__ float sB[256];
  __shared__ int lastFlag;
  const int tid = threadIdx.x, b = blockIdx.x;

  float logAcc = 0.f;
  if (tid < 128) {
    const int row = b * 128 + tid;
    const float4* rp = reinterpret_cast<const float4*>(rowPart + (size_t)row * NP);
    float s = 0.f;
#pragma unroll
    for (int c = 0; c < NP / 4; ++c) {
      float4 v = rp[c];
      s += (v.x + v.y) + (v.z + v.w);
    }
    logAcc = logf(s - EXP10);
  }
  float cross = 0.f;
  if (tid < 64) {
    const int u = b * 64 + tid;
    const unsigned* r0 = reinterpret_cast<const unsigned*>(Gb + (size_t)u * CDIM);
    const unsigned* r1 =
        reinterpret_cast<const unsigned*>(Gb + (size_t)(u + NLOC) * CDIM);
#pragma unroll
    for (int c = 0; c < 32; ++c) {
      unsigned a = r0[c], bb = r1[c];
      cross += bf2f(a & 0xffffu) * bf2f(bb & 0xffffu) + bf2f(a >> 16) * bf2f(bb >> 16);
    }
  }
  sA[tid] = logAcc;
  sB[tid] = cross;
  __syncthreads();
  for (int s = 128; s > 0; s >>= 1) {
    if (tid < s) { sA[tid] += sA[tid + s]; sB[tid] += sB[tid + s]; }
    __syncthreads();
  }
  if (tid == 0) {
    __hip_atomic_store(&partA[b], sA[0], __ATOMIC_RELAXED, __HIP_MEMORY_SCOPE_AGENT);
    __hip_atomic_store(&partB[b], sB[0], __ATOMIC_RELAXED, __HIP_MEMORY_SCOPE_AGENT);
    __threadfence();                          // release partials device-wide
    unsigned old = atomicAdd(counter, 1u);    // device-scope by default
    lastFlag = (old == 63u) ? 1 : 0;
  }
  __syncthreads();

  if (lastFlag && tid < 64) {
    float a = __hip_atomic_load(&partA[tid], __ATOMIC_RELAXED, __HIP_MEMORY_SCOPE_AGENT);
    float c = __hip_atomic_load(&partB[tid], __ATOMIC_RELAXED, __HIP_MEMORY_SCOPE_AGENT);
#pragma unroll
    for (int s = 1; s < 64; s <<= 1) {        // fixed-order butterfly
      a += __shfl_xor(a, s, 64);
      c += __shfl_xor(c, s, 64);
    }
    if (tid == 0) out[0] = (a - 2.0f * TINV * c) / (float)NROW;
  }
}

// ---------------------------------------------------------------------------
extern "C" void kernel_launch(void* const* d_in, const int* in_sizes, int n_in,
                              void* d_out, int out_size, void* d_ws, size_t ws_size,
                              hipStream_t stream) {
  const float* emb0 = (const float*)d_in[0];
  const float* emb1 = (const float*)d_in[1];
  const float* loc0 = (const float*)d_in[2];
  const float* loc1 = (const float*)d_in[3];
  float* out = (float*)d_out;
  char* ws = (char*)d_ws;

  // Layout: Ga 1MB | Gb 1MB | rowPart 2MB | partA | partB | counter
  u16* Ga           = (u16*)ws;
  u16* Gb           = (u16*)(ws + (1ull << 20));
  float* rowPart    = (float*)(ws + (2ull << 20));
  float* partA      = (float*)(ws + (4ull << 20));
  float* partB      = (float*)(ws + (4ull << 20) + 256);
  unsigned* counter = (unsigned*)(ws + (4ull << 20) + 512);

  dim3 gg(128, 4);
  gatherc_kernel<<<gg, 256, 0, stream>>>(emb0, emb1, loc0, loc1, Ga, Gb, counter);
  simsum_tri_kernel<<<NPAIR, 256, 0, stream>>>(Ga, Gb, rowPart);
  finpart_kernel<<<64, 256, 0, stream>>>(Gb, rowPart, partA, partB, counter, out);
}